// Round 6
// baseline (285.536 us; speedup 1.0000x reference)
//
#include <hip/hip_runtime.h>
#include <cstdint>

#define M_DIM 65536
#define N_DIM 512
#define K_DIM 512
#define BM 128
#define BN 128
#define BK 32
#define NRING 2
#define A_TILE_B (BM * BK * 4)        // 16384 B per f32 A-tile
#define B_TILE_B (4 * BN * 16)        // 8192 B per bf16 B-tile
#define LDS_B_OFF (NRING * A_TILE_B)  // 32768
#define TILE_ADV (8 * BM * K_DIM * 4) // A byte advance between consecutive t (8 m-tiles)

typedef float f32x4 __attribute__((ext_vector_type(4)));
typedef __bf16 bf16x8 __attribute__((ext_vector_type(8)));
typedef unsigned short us8 __attribute__((ext_vector_type(8)));

__device__ __forceinline__ unsigned short f2bf(float f) {
  unsigned int u = __builtin_bit_cast(unsigned int, f);
  u += 0x7fffu + ((u >> 16) & 1u);  // round-to-nearest-even
  return (unsigned short)(u >> 16);
}

__device__ __forceinline__ unsigned int cvt_pk_bf16(float lo, float hi) {
  unsigned int r;
  asm("v_cvt_pk_bf16_f32 %0, %1, %2" : "=v"(r) : "v"(lo), "v"(hi));
  return r;
}

__device__ __forceinline__ void async16(const void* g, void* l) {
  __builtin_amdgcn_global_load_lds(
      (const __attribute__((address_space(1))) void*)g,
      (__attribute__((address_space(3))) void*)l, 16, 0, 0);
}

// ---------------------------------------------------------------------------
// Prep: WCT2[(kq*512 + (o*8+kb))*8 + i] = bf16(wc[i][kb]) for (o, n_in=kq).
// ---------------------------------------------------------------------------
__global__ void clifford_prep(const float* __restrict__ weight,
                              const float* __restrict__ bias,
                              const float* __restrict__ row_scale,
                              const float* __restrict__ col_scale,
                              const float* __restrict__ bias_shift,
                              unsigned short* __restrict__ WCT2,
                              float* __restrict__ bias2) {
  const int t = blockIdx.x * 256 + threadIdx.x;
  if (t < 512) {
    const int o = t >> 3, k = t & 7;
    bias2[t] = bias[t] + (k == 0 ? bias_shift[o] : 0.0f);
  }
  if (t >= 64 * 64) return;
  const int o = t >> 6, n = t & 63;  // n = input feature = kq
  const float rs = row_scale[o], cs = col_scale[n];
  float w[8];
#pragma unroll
  for (int j = 0; j < 8; ++j) {
    float v = weight[(size_t)t * 8 + j] * rs * cs;
    w[j] = (v != v) ? 0.0f : v;  // nan_to_num
  }
  constexpr int TI[64] = {0,1,2,3,4,5,6,7, 0,1,2,4,3,5,6,7, 0,2,1,4,3,6,5,7,
                          0,3,1,5,2,6,4,7, 0,4,1,2,3,7,5,6, 0,5,1,3,2,7,4,6,
                          0,6,2,3,1,7,4,5, 0,7,1,6,2,5,3,4};
  constexpr int TJ[64] = {0,1,2,3,4,5,6,7, 1,0,4,2,5,3,7,6, 2,0,4,1,6,3,7,5,
                          3,0,5,1,6,2,7,4, 4,0,2,1,7,3,6,5, 5,0,3,1,7,2,6,4,
                          6,0,3,2,7,1,5,4, 7,0,6,1,5,2,4,3};
  constexpr int TK[64] = {0,0,0,0,0,0,0,0, 1,1,1,1,1,1,1,1, 2,2,2,2,2,2,2,2,
                          3,3,3,3,3,3,3,3, 4,4,4,4,4,4,4,4, 5,5,5,5,5,5,5,5,
                          6,6,6,6,6,6,6,6, 7,7,7,7,7,7,7,7};
  constexpr float TS[64] = {1,1,1,1,-1,-1,-1,-1, 1,1,-1,1,-1,1,-1,-1, 1,1,1,-1,-1,1,1,1,
                            1,1,1,-1,1,-1,-1,-1, 1,1,1,-1,1,1,-1,1,  1,1,1,-1,-1,-1,1,-1,
                            1,1,1,-1,1,1,-1,1,   1,1,1,1,-1,-1,1,1};
  float wc[8][8];
#pragma unroll
  for (int i = 0; i < 8; ++i)
#pragma unroll
    for (int k = 0; k < 8; ++k) wc[i][k] = 0.0f;
#pragma unroll
  for (int e = 0; e < 64; ++e) wc[TI[e]][TK[e]] += TS[e] * w[TJ[e]];
#pragma unroll
  for (int kb = 0; kb < 8; ++kb)
#pragma unroll
    for (int i = 0; i < 8; ++i)
      WCT2[((size_t)n * N_DIM + o * 8 + kb) * 8 + i] = f2bf(wc[i][kb]);
}

// ---------------------------------------------------------------------------
// GEMM: out = x * W^T (+bias2). PERSISTENT blocks: grid=512 (2/CU), each block
// keeps its n-tile and walks 4 m-tiles (mt = mc*32 + xcd + 8t: the 4 n-tile
// siblings of an m-tile stay co-XCD and co-temporal -> x L2 reuse). The DMA
// ring (NRING=2, counted vmcnt, never 0 mid-stream) runs CONTINUOUSLY across
// m-tile boundaries: tile t's epilogue stores overlap tiles (t+1) loads, and
// the pipeline fills once instead of 8x per CU. MFMA operands swapped
// (mfma(B,A) -> transposed C/D: lane holds 4 consecutive n) so the epilogue
// is 16 dwordx4 stores -> exactly countable in vmcnt: vmcnt(22) for 2 steps
// after an epilogue (16 stores + next tile in flight), vmcnt(6) otherwise.
// ---------------------------------------------------------------------------
__global__ __launch_bounds__(256, 2) void clifford_gemm(
    const float* __restrict__ x, const unsigned short* __restrict__ WCT2,
    const float* __restrict__ bias2, float* __restrict__ out) {
  __shared__ __align__(16) char lds[NRING * A_TILE_B + NRING * B_TILE_B];  // 48 KB

  const int tid = threadIdx.x;
  const int lane = tid & 63;
  const int wv = tid >> 6;

  const int bid = blockIdx.x;  // 512 blocks
  const int xcd = bid & 7;
  const int jj = bid >> 3;     // 0..63
  const int nt = jj & 3;
  const int mc = jj >> 2;      // 0..15
  const int n0 = nt * BN;
  const size_t m0r = (size_t)(mc * 32 + xcd) * BM;  // t=0 base m-row

  const int wm = (wv & 1) * 64;
  const int wn = (wv >> 1) * 64;
  const int lm = lane & 15;
  const int kg = lane >> 4;  // 0..3

  // A DMA source (both-sides swizzle, as r4/r5)
  const int asw = ((lane & 7) ^ (lane >> 3)) << 4;
  const char* aT[4];
#pragma unroll
  for (int c = 0; c < 4; ++c)
    aT[c] = (const char*)x +
            (m0r + wv * 32 + c * 8 + (lane >> 3)) * (size_t)(K_DIM * 4) + asw;

  // B DMA source (identical every m-tile; WCT2 is L2-resident)
  const char* bSrc[2];
#pragma unroll
  for (int c = 0; c < 2; ++c) {
    const int q = c * 2 + (wv >> 1);
    const int nl = (wv & 1) * 64 + lane;
    bSrc[c] = (const char*)WCT2 + ((size_t)q * N_DIM + n0 + nl) * 16;
  }

  // LDS read offsets (unchanged swizzle math)
  const int aRd0 = (wm + lm) * 128 + ((kg * 32 + 0) ^ ((lm & 7) << 4));
  const int aRd1 = (wm + lm) * 128 + ((kg * 32 + 16) ^ ((lm & 7) << 4));
  const int bRd = kg * 2048 + (wn + lm) * 16;

  // hoisted bias vectors: col base = n0 + wn + ni*16 + kg*4
  f32x4 bv[4];
#pragma unroll
  for (int ni = 0; ni < 4; ++ni)
    bv[ni] = *(const f32x4*)(bias2 + n0 + wn + ni * 16 + kg * 4);

  const f32x4 zero = {0.f, 0.f, 0.f, 0.f};
  f32x4 acc[4][4];
#pragma unroll
  for (int i = 0; i < 4; ++i)
#pragma unroll
    for (int j = 0; j < 4; ++j) acc[i][j] = zero;

  auto issueTile = [&](const char* const ap[4], int ksIdx) {
    const int slot = ksIdx & 1;
    char* da = &lds[slot * A_TILE_B + wv * 4096];
#pragma unroll
    for (int c = 0; c < 4; ++c)
      async16(ap[c] + ksIdx * (BK * 4), da + c * 1024);
    char* db = &lds[LDS_B_OFF + slot * B_TILE_B + wv * 1024];
#pragma unroll
    for (int c = 0; c < 2; ++c)
      async16(bSrc[c] + (size_t)ksIdx * (4 * N_DIM * 16), db + c * 4096);
  };

  // prologue: fill the 2-deep ring once for the whole kernel
  issueTile(aT, 0);
  issueTile(aT, 1);

  for (int t = 0; t < 4; ++t) {
    const char* aT2[4];
#pragma unroll
    for (int c = 0; c < 4; ++c) aT2[c] = aT[c] + TILE_ADV;

#pragma unroll
    for (int ks = 0; ks < 16; ++ks) {
      const int slot = ks & 1;
      // counted waits: tile (t,ks) must be in LDS; stores + next tile may
      // stay in flight. In-order vmcnt retirement makes the counts exact.
      if (t == 3 && ks == 15)
        asm volatile("s_waitcnt vmcnt(0)" ::: "memory");
      else if (ks <= 1 && t > 0)
        asm volatile("s_waitcnt vmcnt(22)" ::: "memory");
      else
        asm volatile("s_waitcnt vmcnt(6)" ::: "memory");
      __builtin_amdgcn_s_barrier();

      f32x4 alo[4], ahi[4];
      us8 bfr[4];
#pragma unroll
      for (int mi = 0; mi < 4; ++mi) {
        alo[mi] = *(const f32x4*)&lds[slot * A_TILE_B + aRd0 + mi * 2048];
        ahi[mi] = *(const f32x4*)&lds[slot * A_TILE_B + aRd1 + mi * 2048];
      }
#pragma unroll
      for (int ni = 0; ni < 4; ++ni)
        bfr[ni] = *(const us8*)&lds[LDS_B_OFF + slot * B_TILE_B + bRd + ni * 256];

      bf16x8 af[4];
#pragma unroll
      for (int mi = 0; mi < 4; ++mi) {
        union { us8 v; unsigned int w[4]; } u;
        u.w[0] = cvt_pk_bf16(alo[mi][0], alo[mi][1]);
        u.w[1] = cvt_pk_bf16(alo[mi][2], alo[mi][3]);
        u.w[2] = cvt_pk_bf16(ahi[mi][0], ahi[mi][1]);
        u.w[3] = cvt_pk_bf16(ahi[mi][2], ahi[mi][3]);
        af[mi] = __builtin_bit_cast(bf16x8, u.v);
      }

      // swapped operands: D^T fragment -> lane holds (m=lm, n=kg*4+rr+16ni)
      __builtin_amdgcn_s_setprio(1);
#pragma unroll
      for (int mi = 0; mi < 4; ++mi)
#pragma unroll
        for (int ni = 0; ni < 4; ++ni)
          acc[mi][ni] = __builtin_amdgcn_mfma_f32_16x16x32_bf16(
              __builtin_bit_cast(bf16x8, bfr[ni]), af[mi], acc[mi][ni], 0, 0, 0);
      __builtin_amdgcn_s_setprio(0);

      __builtin_amdgcn_sched_barrier(0);
      __builtin_amdgcn_s_barrier();

      // continuous prefetch across the m-tile boundary
      if (ks < 14)
        issueTile(aT, ks + 2);
      else if (t < 3)
        issueTile(aT2, ks - 14);

      // epilogue for tile t: 16 dwordx4 stores, overlapping (t+1) loads
      if (ks == 15) {
        float* ob = out + (m0r + (size_t)t * 1024 + wm + lm) * N_DIM +
                    n0 + wn + kg * 4;
#pragma unroll
        for (int mi = 0; mi < 4; ++mi)
#pragma unroll
          for (int ni = 0; ni < 4; ++ni) {
            f32x4 v = acc[mi][ni] + bv[ni];
            *(f32x4*)(ob + mi * 16 * N_DIM + ni * 16) = v;
            acc[mi][ni] = zero;
          }
      }
    }
#pragma unroll
    for (int c = 0; c < 4; ++c) aT[c] = aT2[c];
  }
}

extern "C" void kernel_launch(void* const* d_in, const int* in_sizes, int n_in,
                              void* d_out, int out_size, void* d_ws, size_t ws_size,
                              hipStream_t stream) {
  const float* x          = (const float*)d_in[0];
  const float* weight     = (const float*)d_in[1];
  const float* bias       = (const float*)d_in[2];
  const float* row_scale  = (const float*)d_in[3];
  const float* col_scale  = (const float*)d_in[4];
  const float* bias_shift = (const float*)d_in[5];

  unsigned short* WCT2 = (unsigned short*)d_ws;                      // 512*512*2 B
  float* bias2 = (float*)((char*)d_ws + (size_t)N_DIM * K_DIM * 2);  // +2 KB

  clifford_prep<<<16, 256, 0, stream>>>(weight, bias, row_scale, col_scale,
                                        bias_shift, WCT2, bias2);
  clifford_gemm<<<512, 256, 0, stream>>>(x, WCT2, bias2, (float*)d_out);
}